// Round 8
// baseline (1424.948 us; speedup 1.0000x reference)
//
#include <hip/hip_runtime.h>
#include <cfloat>
#include <cmath>

#define HC 80   // H*C
#define HH 8    // heads
#define CC 10   // channels per head

// +4-float gap every 32 floats: spreads stride-32 column patterns across banks
#define GAP(c) ((c) + ((((c) >> 5)) << 2))

// ---------------- CSR build ----------------

__global__ void hist_kernel(const int* __restrict__ dst, int* __restrict__ counts, int E) {
    int i = blockIdx.x * blockDim.x + threadIdx.x;
    int stride = gridDim.x * blockDim.x;
    for (; i < E; i += stride) atomicAdd(&counts[dst[i]], 1);
}

__global__ void scan_kernel(const int* __restrict__ in, int* __restrict__ out, int n) {
    __shared__ int wsum[16];
    __shared__ int carry;
    if (threadIdx.x == 0) carry = 0;
    __syncthreads();
    int lane = threadIdx.x & 63, w = threadIdx.x >> 6;
    for (int base = 0; base < n; base += 1024) {
        int i = base + (int)threadIdx.x;
        int v = (i < n) ? in[i] : 0;
        int s = v;
        #pragma unroll
        for (int off = 1; off < 64; off <<= 1) {
            int t = __shfl_up(s, off, 64);
            if (lane >= off) s += t;
        }
        if (lane == 63) wsum[w] = s;
        __syncthreads();
        if (w == 0) {
            int ws = (lane < 16) ? wsum[lane] : 0;
            int ss = ws;
            #pragma unroll
            for (int off = 1; off < 16; off <<= 1) {
                int t = __shfl_up(ss, off, 64);
                if (lane >= off) ss += t;
            }
            if (lane < 16) wsum[lane] = ss - ws;
        }
        __syncthreads();
        int c = carry;
        if (i < n) out[i] = c + wsum[w] + s - v;
        __syncthreads();
        if (threadIdx.x == 1023) carry = c + wsum[15] + s;
    }
    __syncthreads();
    if (threadIdx.x == 0) out[n] = carry;
}

__global__ void scatter_kernel(const int* __restrict__ src, const int* __restrict__ dst,
                               int* __restrict__ cursor, int* __restrict__ csr, int E) {
    int i = blockIdx.x * blockDim.x + threadIdx.x;
    int stride = gridDim.x * blockDim.x;
    for (; i < E; i += stride) {
        int p = atomicAdd(&cursor[dst[i]], 1);
        csr[p] = src[i];
    }
}

// ---------------- degree bucket-sort (equalize degree within a wave's 8 groups) ----------------

__global__ void dhist_kernel(const int* __restrict__ counts, int* __restrict__ dhist, int N) {
    int i = blockIdx.x * blockDim.x + threadIdx.x;
    int st = gridDim.x * blockDim.x;
    for (; i < N; i += st) atomicAdd(&dhist[min(counts[i], 63)], 1);
}

__global__ void dscan_kernel(const int* __restrict__ dhist, int* __restrict__ dcur) {
    int lane = threadIdx.x;      // 64 threads
    int v = dhist[lane], s = v;
    #pragma unroll
    for (int off = 1; off < 64; off <<= 1) {
        int t = __shfl_up(s, off, 64);
        if (lane >= off) s += t;
    }
    dcur[lane] = s - v;          // exclusive
}

__global__ void dorder_kernel(const int* __restrict__ counts, int* __restrict__ dcur,
                              int* __restrict__ order, int N) {
    int i = blockIdx.x * blockDim.x + threadIdx.x;
    int st = gridDim.x * blockDim.x;
    for (; i < N; i += st) {
        int b = min(counts[i], 63);
        int p = atomicAdd(&dcur[b], 1);
        order[p] = i;
    }
}

// ---------------- dual GEMM: [Yl|Yr] = X @ [Wl|Wr]  (X:[N,K], W:[K,80] each) ----------------
// 320 threads, tile 128 rows x 160 cols, BK=16, thread tile 8x8.
// Reg-staged pipeline + double-buffered LDS: issue global loads for tile t+1,
// compute tile t, then LDS-write t+1; one barrier per iteration.

__global__ __launch_bounds__(320, 4) void gemm_big(
    const float* __restrict__ X, const float* __restrict__ Wl, const float* __restrict__ Wr,
    float* __restrict__ Yl, float* __restrict__ Yr, int N, int K)
{
    __shared__ float xs[2][16 * 140];   // GAP(127)=139
    __shared__ float ws[2][16 * 176];   // GAP(159)=175
    const int tid = threadIdx.x;
    const int rt = tid & 15;            // broadcast dim within wave
    const int cg = tid >> 4;            // 0..19
    const int r0 = rt * 8;
    const int c0 = cg * 8;
    const int rG0 = GAP(r0);
    const int cG0 = GAP(c0);
    const int base = blockIdx.x * 128;

    // staging index map: X tile = 512 float4 (128r x 4), W tile = 640 float4 (16r x 40)
    const int xr_0 = tid >> 2,         xk0 = (tid & 3) << 2;
    const int xr_1 = (tid + 320) >> 2, xk1 = ((tid + 320) & 3) << 2;
    const bool hasX1 = tid < 192;
    const int wrow0 = tid / 40,      wc0 = tid % 40;
    const int wrow1 = 8 + tid / 40,  wc1 = tid % 40;

    float4 vx0, vx1, vw0, vw1;

    auto loadTile = [&](int k0) {
        int n0 = base + xr_0; if (n0 >= N) n0 = N - 1;
        vx0 = *(const float4*)(X + (size_t)n0 * K + k0 + xk0);
        if (hasX1) {
            int n1 = base + xr_1; if (n1 >= N) n1 = N - 1;
            vx1 = *(const float4*)(X + (size_t)n1 * K + k0 + xk1);
        }
        vw0 = (wc0 < 20) ? *(const float4*)(Wl + (size_t)(k0 + wrow0) * HC + wc0 * 4)
                         : *(const float4*)(Wr + (size_t)(k0 + wrow0) * HC + (wc0 - 20) * 4);
        vw1 = (wc1 < 20) ? *(const float4*)(Wl + (size_t)(k0 + wrow1) * HC + wc1 * 4)
                         : *(const float4*)(Wr + (size_t)(k0 + wrow1) * HC + (wc1 - 20) * 4);
    };
    auto storeTile = [&](int b) {
        int rg = GAP(xr_0);
        xs[b][(xk0 + 0) * 140 + rg] = vx0.x;
        xs[b][(xk0 + 1) * 140 + rg] = vx0.y;
        xs[b][(xk0 + 2) * 140 + rg] = vx0.z;
        xs[b][(xk0 + 3) * 140 + rg] = vx0.w;
        if (hasX1) {
            int rg1 = GAP(xr_1);
            xs[b][(xk1 + 0) * 140 + rg1] = vx1.x;
            xs[b][(xk1 + 1) * 140 + rg1] = vx1.y;
            xs[b][(xk1 + 2) * 140 + rg1] = vx1.z;
            xs[b][(xk1 + 3) * 140 + rg1] = vx1.w;
        }
        *(float4*)&ws[b][wrow0 * 176 + GAP(wc0 * 4)] = vw0;
        *(float4*)&ws[b][wrow1 * 176 + GAP(wc1 * 4)] = vw1;
    };

    float4 acc[8][2];
    #pragma unroll
    for (int i = 0; i < 8; ++i) {
        acc[i][0] = make_float4(0.f, 0.f, 0.f, 0.f);
        acc[i][1] = make_float4(0.f, 0.f, 0.f, 0.f);
    }

    loadTile(0);
    storeTile(0);
    __syncthreads();

    const int nT = K >> 4;
    for (int t = 0; t < nT; ++t) {
        const int cur = t & 1;
        if (t + 1 < nT) loadTile((t + 1) << 4);

        #pragma unroll 4
        for (int k = 0; k < 16; ++k) {
            const float* xk = &xs[cur][k * 140 + rG0];
            float4 xa = *(const float4*)(xk);
            float4 xb = *(const float4*)(xk + 4);
            const float* wk = &ws[cur][k * 176 + cG0];
            float4 wa = *(const float4*)(wk);
            float4 wb = *(const float4*)(wk + 4);
            float xv[8] = {xa.x, xa.y, xa.z, xa.w, xb.x, xb.y, xb.z, xb.w};
            #pragma unroll
            for (int i = 0; i < 8; ++i) {
                acc[i][0].x += xv[i] * wa.x;
                acc[i][0].y += xv[i] * wa.y;
                acc[i][0].z += xv[i] * wa.z;
                acc[i][0].w += xv[i] * wa.w;
                acc[i][1].x += xv[i] * wb.x;
                acc[i][1].y += xv[i] * wb.y;
                acc[i][1].z += xv[i] * wb.z;
                acc[i][1].w += xv[i] * wb.w;
            }
        }

        if (t + 1 < nT) storeTile(cur ^ 1);
        __syncthreads();
    }

    float* Ybase = (cg < 10) ? (Yl + c0) : (Yr + (c0 - 80));
    #pragma unroll
    for (int i = 0; i < 8; ++i) {
        int n = base + r0 + i;
        if (n < N) {
            float* yp = Ybase + (size_t)n * HC;
            *(float4*)yp = acc[i][0];
            *(float4*)(yp + 4) = acc[i][1];
        }
    }
}

// ---------------- fused per-node attention + softmax + aggregate + elu ----------------
// Lane = head: 8-lane group per node (degree-sorted order), lane h holds head h's
// 10 channels in registers; online softmax lane-local, defer-max THR=8 (exp2 domain).

__global__ __launch_bounds__(256) void aggregate_kernel(
    const float* __restrict__ xl, const float* __restrict__ xr,
    const int* __restrict__ csr, const int* __restrict__ offsets,
    const int* __restrict__ order,
    const float* __restrict__ att, const float* __restrict__ bias,
    float* __restrict__ xout, int N) {
    const int tid = threadIdx.x;
    const int idx = blockIdx.x * 32 + (tid >> 3);
    const int h = tid & 7;
    if (idx >= N) return;
    const int n = order[idx];
    const float L2E = 1.4426950408889634f;

    float attv[10], xrv[10];
    #pragma unroll
    for (int j = 0; j < 5; ++j) {
        float2 a = *(const float2*)(att + h * CC + 2 * j);
        attv[2 * j] = a.x * L2E; attv[2 * j + 1] = a.y * L2E;
        float2 r = *(const float2*)(xr + (size_t)n * HC + h * CC + 2 * j);
        xrv[2 * j] = r.x; xrv[2 * j + 1] = r.y;
    }

    const int beg = offsets[n], end = offsets[n + 1];
    float m = -1e30f, s = 0.f;
    float acc[10];
    #pragma unroll
    for (int j = 0; j < 10; ++j) acc[j] = 0.f;

    int i = beg - 1;                   // iteration -1 = self loop
    while (__any(i < end)) {
        if (i < end) {
            int src = (i < beg) ? n : csr[i];
            const float* xp = xl + (size_t)src * HC + h * CC;
            float xv[10];
            #pragma unroll
            for (int j = 0; j < 5; ++j) {
                float2 v = *(const float2*)(xp + 2 * j);
                xv[2 * j] = v.x; xv[2 * j + 1] = v.y;
            }
            float e = 0.f;
            #pragma unroll
            for (int j = 0; j < 10; ++j) {
                float t = xv[j] + xrv[j];
                float l = 0.6f * t + 0.4f * fabsf(t);   // leaky_relu(t, 0.2)
                e += l * attv[j];
            }
            float diff = e - m;
            if (__builtin_expect(diff > 8.0f, 0)) {     // rare after iter 0
                float sc = exp2f(-diff);
                s = s * sc + 1.f;
                #pragma unroll
                for (int j = 0; j < 10; ++j) acc[j] = acc[j] * sc + xv[j];
                m = e;
            } else {
                float p = exp2f(diff);
                s += p;
                #pragma unroll
                for (int j = 0; j < 10; ++j) acc[j] += p * xv[j];
            }
        }
        ++i;
    }

    float inv = 1.f / s;
    float* op = xout + (size_t)n * HC + h * CC;
    #pragma unroll
    for (int j = 0; j < 5; ++j) {
        float2 b = *(const float2*)(bias + h * CC + 2 * j);
        float o0 = acc[2 * j] * inv + b.x;
        float o1 = acc[2 * j + 1] * inv + b.y;
        o0 = (o0 > 0.f) ? o0 : (__expf(o0) - 1.f);      // elu
        o1 = (o1 > 0.f) ? o1 : (__expf(o1) - 1.f);
        *(float2*)(op + 2 * j) = make_float2(o0, o1);
    }
}

extern "C" void kernel_launch(void* const* d_in, const int* in_sizes, int n_in,
                              void* d_out, int out_size, void* d_ws, size_t ws_size,
                              hipStream_t stream) {
    int N = out_size / HC;       // 100000
    int E = in_sizes[1] / 2;     // 1000000
    int F = in_sizes[0] / N;     // 128

    const float* x   = (const float*)d_in[0];
    const int*   ei  = (const int*)d_in[1];
    const float* Wl[3]  = {(const float*)d_in[2], (const float*)d_in[6],  (const float*)d_in[10]};
    const float* Wr[3]  = {(const float*)d_in[3], (const float*)d_in[7],  (const float*)d_in[11]};
    const float* att[3] = {(const float*)d_in[4], (const float*)d_in[8],  (const float*)d_in[12]};
    const float* bb[3]  = {(const float*)d_in[5], (const float*)d_in[9],  (const float*)d_in[13]};

    size_t NF = (size_t)N * HC;
    float* xl = (float*)d_ws;
    float* xr = xl + NF;
    float* xb = xr + NF;
    int* counts  = (int*)(xb + NF);
    int* offsets = counts + (N + 1);
    int* cursor  = offsets + (N + 1);
    int* csr     = cursor + N;
    int* dhist   = csr + E;
    int* dcur    = dhist + 64;
    int* order   = dcur + 64;

    const int* srcv = ei;
    const int* dstv = ei + E;

    hipMemsetAsync(counts, 0, (size_t)(N + 1) * sizeof(int), stream);
    hipMemsetAsync(dhist, 0, 64 * sizeof(int), stream);
    hist_kernel<<<1024, 256, 0, stream>>>(dstv, counts, E);
    scan_kernel<<<1, 1024, 0, stream>>>(counts, offsets, N);
    hipMemcpyAsync(cursor, offsets, (size_t)N * sizeof(int), hipMemcpyDeviceToDevice, stream);
    scatter_kernel<<<1024, 256, 0, stream>>>(srcv, dstv, cursor, csr, E);
    dhist_kernel<<<512, 256, 0, stream>>>(counts, dhist, N);
    dscan_kernel<<<1, 64, 0, stream>>>(dhist, dcur);
    dorder_kernel<<<512, 256, 0, stream>>>(counts, dcur, order, N);

    for (int l = 0; l < 3; ++l) {
        const float* xin = (l == 0) ? x : xb;
        int K = (l == 0) ? F : HC;
        gemm_big<<<(N + 127) / 128, 320, 0, stream>>>(xin, Wl[l], Wr[l], xl, xr, N, K);
        float* xout = (l == 2) ? (float*)d_out : xb;
        aggregate_kernel<<<(N + 31) / 32, 256, 0, stream>>>(xl, xr, csr, offsets, order,
                                                            att[l], bb[l], xout, N);
    }
}

// Round 10
// 777.548 us; speedup vs baseline: 1.8326x; 1.8326x over previous
//
#include <hip/hip_runtime.h>
#include <cfloat>
#include <cmath>

#define HC 80   // H*C
#define HH 8    // heads
#define CC 10   // channels per head

// +4-float gap every 32 floats: spreads stride-32 column patterns across banks
#define GAP(c) ((c) + ((((c) >> 5)) << 2))

// ---------------- CSR build ----------------

__global__ void hist_kernel(const int* __restrict__ dst, int* __restrict__ counts, int E) {
    int i = blockIdx.x * blockDim.x + threadIdx.x;
    int stride = gridDim.x * blockDim.x;
    for (; i < E; i += stride) atomicAdd(&counts[dst[i]], 1);
}

__global__ void scan_kernel(const int* __restrict__ in, int* __restrict__ out, int n) {
    __shared__ int wsum[16];
    __shared__ int carry;
    if (threadIdx.x == 0) carry = 0;
    __syncthreads();
    int lane = threadIdx.x & 63, w = threadIdx.x >> 6;
    for (int base = 0; base < n; base += 1024) {
        int i = base + (int)threadIdx.x;
        int v = (i < n) ? in[i] : 0;
        int s = v;
        #pragma unroll
        for (int off = 1; off < 64; off <<= 1) {
            int t = __shfl_up(s, off, 64);
            if (lane >= off) s += t;
        }
        if (lane == 63) wsum[w] = s;
        __syncthreads();
        if (w == 0) {
            int ws = (lane < 16) ? wsum[lane] : 0;
            int ss = ws;
            #pragma unroll
            for (int off = 1; off < 16; off <<= 1) {
                int t = __shfl_up(ss, off, 64);
                if (lane >= off) ss += t;
            }
            if (lane < 16) wsum[lane] = ss - ws;
        }
        __syncthreads();
        int c = carry;
        if (i < n) out[i] = c + wsum[w] + s - v;
        __syncthreads();
        if (threadIdx.x == 1023) carry = c + wsum[15] + s;
    }
    __syncthreads();
    if (threadIdx.x == 0) out[n] = carry;
}

__global__ void scatter_kernel(const int* __restrict__ src, const int* __restrict__ dst,
                               int* __restrict__ cursor, int* __restrict__ csr, int E) {
    int i = blockIdx.x * blockDim.x + threadIdx.x;
    int stride = gridDim.x * blockDim.x;
    for (; i < E; i += stride) {
        int p = atomicAdd(&cursor[dst[i]], 1);
        csr[p] = src[i];
    }
}

// ---------------- degree bucket-sort (hierarchical: LDS first, few global atomics) ----------------

__global__ __launch_bounds__(256) void dhist_kernel(const int* __restrict__ counts,
                                                    int* __restrict__ dhist, int N) {
    __shared__ int lh[64];
    if (threadIdx.x < 64) lh[threadIdx.x] = 0;
    __syncthreads();
    int i = blockIdx.x * blockDim.x + threadIdx.x;
    int st = gridDim.x * blockDim.x;
    for (; i < N; i += st) atomicAdd(&lh[min(counts[i], 63)], 1);
    __syncthreads();
    if (threadIdx.x < 64) atomicAdd(&dhist[threadIdx.x], lh[threadIdx.x]);
}

__global__ void dscan_kernel(const int* __restrict__ dhist, int* __restrict__ dcur) {
    int lane = threadIdx.x;      // 64 threads
    int v = dhist[lane], s = v;
    #pragma unroll
    for (int off = 1; off < 64; off <<= 1) {
        int t = __shfl_up(s, off, 64);
        if (lane >= off) s += t;
    }
    dcur[lane] = s - v;          // exclusive
}

// each block owns a contiguous node range; 2-pass: LDS count -> reserve chunk -> distribute
__global__ __launch_bounds__(256) void dorder_kernel(const int* __restrict__ counts,
                                                     int* __restrict__ dcur,
                                                     int* __restrict__ order, int N) {
    __shared__ int lh[64];
    __shared__ int lcur[64];
    int per = (N + gridDim.x - 1) / gridDim.x;
    int lo = blockIdx.x * per, hi = min(lo + per, N);
    if (threadIdx.x < 64) lh[threadIdx.x] = 0;
    __syncthreads();
    for (int i = lo + (int)threadIdx.x; i < hi; i += blockDim.x)
        atomicAdd(&lh[min(counts[i], 63)], 1);
    __syncthreads();
    if (threadIdx.x < 64) lcur[threadIdx.x] = atomicAdd(&dcur[threadIdx.x], lh[threadIdx.x]);
    __syncthreads();
    for (int i = lo + (int)threadIdx.x; i < hi; i += blockDim.x) {
        int b = min(counts[i], 63);
        int p = atomicAdd(&lcur[b], 1);
        order[p] = i;
    }
}

// ---------------- dual GEMM: [Yl|Yr] = X @ [Wl|Wr]  (X:[N,K], W:[K,80] each) ----------------
// 320 threads, tile 128 rows x 160 cols, BK=16, thread tile 8x8.
// Reg-staged pipeline + double-buffered LDS: issue global loads for tile t+1,
// compute tile t, then LDS-write t+1; one barrier per iteration.

__global__ __launch_bounds__(320, 4) void gemm_big(
    const float* __restrict__ X, const float* __restrict__ Wl, const float* __restrict__ Wr,
    float* __restrict__ Yl, float* __restrict__ Yr, int N, int K)
{
    __shared__ float xs[2][16 * 140];   // GAP(127)=139
    __shared__ float ws[2][16 * 176];   // GAP(159)=175
    const int tid = threadIdx.x;
    const int rt = tid & 15;            // broadcast dim within wave
    const int cg = tid >> 4;            // 0..19
    const int r0 = rt * 8;
    const int c0 = cg * 8;
    const int rG0 = GAP(r0);
    const int cG0 = GAP(c0);
    const int base = blockIdx.x * 128;

    // staging index map: X tile = 512 float4 (128r x 4), W tile = 640 float4 (16r x 40)
    const int xr_0 = tid >> 2,         xk0 = (tid & 3) << 2;
    const int xr_1 = (tid + 320) >> 2, xk1 = ((tid + 320) & 3) << 2;
    const bool hasX1 = tid < 192;
    const int wrow0 = tid / 40,      wc0 = tid % 40;
    const int wrow1 = 8 + tid / 40,  wc1 = tid % 40;

    float4 vx0, vx1, vw0, vw1;

    auto loadTile = [&](int k0) {
        int n0 = base + xr_0; if (n0 >= N) n0 = N - 1;
        vx0 = *(const float4*)(X + (size_t)n0 * K + k0 + xk0);
        if (hasX1) {
            int n1 = base + xr_1; if (n1 >= N) n1 = N - 1;
            vx1 = *(const float4*)(X + (size_t)n1 * K + k0 + xk1);
        }
        vw0 = (wc0 < 20) ? *(const float4*)(Wl + (size_t)(k0 + wrow0) * HC + wc0 * 4)
                         : *(const float4*)(Wr + (size_t)(k0 + wrow0) * HC + (wc0 - 20) * 4);
        vw1 = (wc1 < 20) ? *(const float4*)(Wl + (size_t)(k0 + wrow1) * HC + wc1 * 4)
                         : *(const float4*)(Wr + (size_t)(k0 + wrow1) * HC + (wc1 - 20) * 4);
    };
    auto storeTile = [&](int b) {
        int rg = GAP(xr_0);
        xs[b][(xk0 + 0) * 140 + rg] = vx0.x;
        xs[b][(xk0 + 1) * 140 + rg] = vx0.y;
        xs[b][(xk0 + 2) * 140 + rg] = vx0.z;
        xs[b][(xk0 + 3) * 140 + rg] = vx0.w;
        if (hasX1) {
            int rg1 = GAP(xr_1);
            xs[b][(xk1 + 0) * 140 + rg1] = vx1.x;
            xs[b][(xk1 + 1) * 140 + rg1] = vx1.y;
            xs[b][(xk1 + 2) * 140 + rg1] = vx1.z;
            xs[b][(xk1 + 3) * 140 + rg1] = vx1.w;
        }
        *(float4*)&ws[b][wrow0 * 176 + GAP(wc0 * 4)] = vw0;
        *(float4*)&ws[b][wrow1 * 176 + GAP(wc1 * 4)] = vw1;
    };

    float4 acc[8][2];
    #pragma unroll
    for (int i = 0; i < 8; ++i) {
        acc[i][0] = make_float4(0.f, 0.f, 0.f, 0.f);
        acc[i][1] = make_float4(0.f, 0.f, 0.f, 0.f);
    }

    loadTile(0);
    storeTile(0);
    __syncthreads();

    const int nT = K >> 4;
    for (int t = 0; t < nT; ++t) {
        const int cur = t & 1;
        if (t + 1 < nT) loadTile((t + 1) << 4);

        #pragma unroll 4
        for (int k = 0; k < 16; ++k) {
            const float* xk = &xs[cur][k * 140 + rG0];
            float4 xa = *(const float4*)(xk);
            float4 xb = *(const float4*)(xk + 4);
            const float* wk = &ws[cur][k * 176 + cG0];
            float4 wa = *(const float4*)(wk);
            float4 wb = *(const float4*)(wk + 4);
            float xv[8] = {xa.x, xa.y, xa.z, xa.w, xb.x, xb.y, xb.z, xb.w};
            #pragma unroll
            for (int i = 0; i < 8; ++i) {
                acc[i][0].x += xv[i] * wa.x;
                acc[i][0].y += xv[i] * wa.y;
                acc[i][0].z += xv[i] * wa.z;
                acc[i][0].w += xv[i] * wa.w;
                acc[i][1].x += xv[i] * wb.x;
                acc[i][1].y += xv[i] * wb.y;
                acc[i][1].z += xv[i] * wb.z;
                acc[i][1].w += xv[i] * wb.w;
            }
        }

        if (t + 1 < nT) storeTile(cur ^ 1);
        __syncthreads();
    }

    float* Ybase = (cg < 10) ? (Yl + c0) : (Yr + (c0 - 80));
    #pragma unroll
    for (int i = 0; i < 8; ++i) {
        int n = base + r0 + i;
        if (n < N) {
            float* yp = Ybase + (size_t)n * HC;
            *(float4*)yp = acc[i][0];
            *(float4*)(yp + 4) = acc[i][1];
        }
    }
}

// ---------------- fused per-node attention + softmax + aggregate + elu ----------------
// Lane = head: 8-lane group per node (degree-sorted order), lane h holds head h's
// 10 channels in registers; online softmax lane-local, defer-max THR=8 (exp2 domain).

__global__ __launch_bounds__(256) void aggregate_kernel(
    const float* __restrict__ xl, const float* __restrict__ xr,
    const int* __restrict__ csr, const int* __restrict__ offsets,
    const int* __restrict__ order,
    const float* __restrict__ att, const float* __restrict__ bias,
    float* __restrict__ xout, int N) {
    const int tid = threadIdx.x;
    const int idx = blockIdx.x * 32 + (tid >> 3);
    const int h = tid & 7;
    if (idx >= N) return;
    const int n = order[idx];
    const float L2E = 1.4426950408889634f;

    float attv[10], xrv[10];
    #pragma unroll
    for (int j = 0; j < 5; ++j) {
        float2 a = *(const float2*)(att + h * CC + 2 * j);
        attv[2 * j] = a.x * L2E; attv[2 * j + 1] = a.y * L2E;
        float2 r = *(const float2*)(xr + (size_t)n * HC + h * CC + 2 * j);
        xrv[2 * j] = r.x; xrv[2 * j + 1] = r.y;
    }

    const int beg = offsets[n], end = offsets[n + 1];
    float m = -1e30f, s = 0.f;
    float acc[10];
    #pragma unroll
    for (int j = 0; j < 10; ++j) acc[j] = 0.f;

    int i = beg - 1;                   // iteration -1 = self loop
    while (__any(i < end)) {
        if (i < end) {
            int src = (i < beg) ? n : csr[i];
            const float* xp = xl + (size_t)src * HC + h * CC;
            float xv[10];
            #pragma unroll
            for (int j = 0; j < 5; ++j) {
                float2 v = *(const float2*)(xp + 2 * j);
                xv[2 * j] = v.x; xv[2 * j + 1] = v.y;
            }
            float e = 0.f;
            #pragma unroll
            for (int j = 0; j < 10; ++j) {
                float t = xv[j] + xrv[j];
                float l = 0.6f * t + 0.4f * fabsf(t);   // leaky_relu(t, 0.2)
                e += l * attv[j];
            }
            float diff = e - m;
            if (__builtin_expect(diff > 8.0f, 0)) {     // rare after iter 0
                float sc = exp2f(-diff);
                s = s * sc + 1.f;
                #pragma unroll
                for (int j = 0; j < 10; ++j) acc[j] = acc[j] * sc + xv[j];
                m = e;
            } else {
                float p = exp2f(diff);
                s += p;
                #pragma unroll
                for (int j = 0; j < 10; ++j) acc[j] += p * xv[j];
            }
        }
        ++i;
    }

    float inv = 1.f / s;
    float* op = xout + (size_t)n * HC + h * CC;
    #pragma unroll
    for (int j = 0; j < 5; ++j) {
        float2 b = *(const float2*)(bias + h * CC + 2 * j);
        float o0 = acc[2 * j] * inv + b.x;
        float o1 = acc[2 * j + 1] * inv + b.y;
        o0 = (o0 > 0.f) ? o0 : (__expf(o0) - 1.f);      // elu
        o1 = (o1 > 0.f) ? o1 : (__expf(o1) - 1.f);
        *(float2*)(op + 2 * j) = make_float2(o0, o1);
    }
}

extern "C" void kernel_launch(void* const* d_in, const int* in_sizes, int n_in,
                              void* d_out, int out_size, void* d_ws, size_t ws_size,
                              hipStream_t stream) {
    int N = out_size / HC;       // 100000
    int E = in_sizes[1] / 2;     // 1000000
    int F = in_sizes[0] / N;     // 128

    const float* x   = (const float*)d_in[0];
    const int*   ei  = (const int*)d_in[1];
    const float* Wl[3]  = {(const float*)d_in[2], (const float*)d_in[6],  (const float*)d_in[10]};
    const float* Wr[3]  = {(const float*)d_in[3], (const float*)d_in[7],  (const float*)d_in[11]};
    const float* att[3] = {(const float*)d_in[4], (const float*)d_in[8],  (const float*)d_in[12]};
    const float* bb[3]  = {(const float*)d_in[5], (const float*)d_in[9],  (const float*)d_in[13]};

    size_t NF = (size_t)N * HC;
    float* xl = (float*)d_ws;
    float* xr = xl + NF;
    float* xb = xr + NF;
    int* counts  = (int*)(xb + NF);
    int* offsets = counts + (N + 1);
    int* cursor  = offsets + (N + 1);
    int* csr     = cursor + N;
    int* dhist   = csr + E;
    int* dcur    = dhist + 64;
    int* order   = dcur + 64;

    const int* srcv = ei;
    const int* dstv = ei + E;

    hipMemsetAsync(counts, 0, (size_t)(N + 1) * sizeof(int), stream);
    hipMemsetAsync(dhist, 0, 64 * sizeof(int), stream);
    hist_kernel<<<1024, 256, 0, stream>>>(dstv, counts, E);
    scan_kernel<<<1, 1024, 0, stream>>>(counts, offsets, N);
    hipMemcpyAsync(cursor, offsets, (size_t)N * sizeof(int), hipMemcpyDeviceToDevice, stream);
    scatter_kernel<<<1024, 256, 0, stream>>>(srcv, dstv, cursor, csr, E);
    dhist_kernel<<<64, 256, 0, stream>>>(counts, dhist, N);
    dscan_kernel<<<1, 64, 0, stream>>>(dhist, dcur);
    dorder_kernel<<<64, 256, 0, stream>>>(counts, dcur, order, N);

    for (int l = 0; l < 3; ++l) {
        const float* xin = (l == 0) ? x : xb;
        int K = (l == 0) ? F : HC;
        gemm_big<<<(N + 127) / 128, 320, 0, stream>>>(xin, Wl[l], Wr[l], xl, xr, N, K);
        float* xout = (l == 2) ? (float*)d_out : xb;
        aggregate_kernel<<<(N + 31) / 32, 256, 0, stream>>>(xl, xr, csr, offsets, order,
                                                            att[l], bb[l], xout, N);
    }
}

// Round 11
// 713.759 us; speedup vs baseline: 1.9964x; 1.0894x over previous
//
#include <hip/hip_runtime.h>
#include <cfloat>
#include <cmath>

#define HC 80   // H*C
#define HH 8    // heads
#define CC 10   // channels per head

typedef __attribute__((ext_vector_type(8))) short bf16x8;
typedef __attribute__((ext_vector_type(4))) float f32x4;

// ---------------- CSR build ----------------

__global__ void hist_kernel(const int* __restrict__ dst, int* __restrict__ counts, int E) {
    int i = blockIdx.x * blockDim.x + threadIdx.x;
    int stride = gridDim.x * blockDim.x;
    for (; i < E; i += stride) atomicAdd(&counts[dst[i]], 1);
}

__global__ void scan_kernel(const int* __restrict__ in, int* __restrict__ out, int n) {
    __shared__ int wsum[16];
    __shared__ int carry;
    if (threadIdx.x == 0) carry = 0;
    __syncthreads();
    int lane = threadIdx.x & 63, w = threadIdx.x >> 6;
    for (int base = 0; base < n; base += 1024) {
        int i = base + (int)threadIdx.x;
        int v = (i < n) ? in[i] : 0;
        int s = v;
        #pragma unroll
        for (int off = 1; off < 64; off <<= 1) {
            int t = __shfl_up(s, off, 64);
            if (lane >= off) s += t;
        }
        if (lane == 63) wsum[w] = s;
        __syncthreads();
        if (w == 0) {
            int ws = (lane < 16) ? wsum[lane] : 0;
            int ss = ws;
            #pragma unroll
            for (int off = 1; off < 16; off <<= 1) {
                int t = __shfl_up(ss, off, 64);
                if (lane >= off) ss += t;
            }
            if (lane < 16) wsum[lane] = ss - ws;
        }
        __syncthreads();
        int c = carry;
        if (i < n) out[i] = c + wsum[w] + s - v;
        __syncthreads();
        if (threadIdx.x == 1023) carry = c + wsum[15] + s;
    }
    __syncthreads();
    if (threadIdx.x == 0) out[n] = carry;
}

__global__ void scatter_kernel(const int* __restrict__ src, const int* __restrict__ dst,
                               int* __restrict__ cursor, int* __restrict__ csr, int E) {
    int i = blockIdx.x * blockDim.x + threadIdx.x;
    int stride = gridDim.x * blockDim.x;
    for (; i < E; i += stride) {
        int p = atomicAdd(&cursor[dst[i]], 1);
        csr[p] = src[i];
    }
}

// ---------------- MFMA dual GEMM: [Yl|Yr] = X @ [Wl|Wr] via bf16 split-precision ----------------
// x = hi + lo (both bf16); D = Xh*Wh + Xl*Wh + Xh*Wl  (error ~K*2^-18, far below threshold).
// Block = 256 thr = 4 waves; wave w owns rows [base+16w, base+16w+16), all 160 cols.
// W chunk (32 k x 160 cols, zero-padded past K) staged in LDS transposed as bf16 hi/lo.
// Fragment maps: A row = lane&15, B col = lane&15, k-octet = lane>>4 (same map for A and B,
// so any k-permutation cancels in the dot). C/D: col=lane&15, row=(lane>>4)*4+reg [m89-verified].

__device__ __forceinline__ unsigned short f2bf(float x) {
    unsigned u = __float_as_uint(x);
    u += 0x7FFF + ((u >> 16) & 1);          // RNE
    return (unsigned short)(u >> 16);
}

__global__ __launch_bounds__(256, 4) void gemm_mfma(
    const float* __restrict__ X, const float* __restrict__ Wl, const float* __restrict__ Wr,
    float* __restrict__ Yl, float* __restrict__ Yr, int N, int K)
{
    __shared__ short wsb[2][160][40];       // [hi/lo][col][k 0..31 + pad], stride 80 B
    const int tid = threadIdx.x;
    const int w = tid >> 6;                 // wave = rowtile
    const int l = tid & 63;
    const int lr = l & 15;                  // A-row / B-col / C-col lane index
    const int lg = l >> 4;                  // k-octet group
    const int base = blockIdx.x * 64;

    f32x4 acc[10];
    #pragma unroll
    for (int ct = 0; ct < 10; ++ct) acc[ct] = (f32x4){0.f, 0.f, 0.f, 0.f};

    int arow = base + w * 16 + lr; if (arow >= N) arow = N - 1;
    const int nch = (K + 31) >> 5;

    for (int ch = 0; ch < nch; ++ch) {
        const int k0 = ch << 5;
        __syncthreads();                    // previous chunk's reads done
        // ---- stage W chunk (coalesced read, convert, transposed LDS write) ----
        for (int e = tid; e < 5120; e += 256) {
            int kr = e / 160, c = e - kr * 160;
            int k = k0 + kr;
            float x = 0.f;
            if (k < K) x = (c < 80) ? Wl[k * 80 + c] : Wr[k * 80 + (c - 80)];
            unsigned short h = f2bf(x);
            wsb[0][c][kr] = (short)h;
            wsb[1][c][kr] = (short)f2bf(x - __uint_as_float((unsigned)h << 16));
        }
        __syncthreads();

        // ---- A fragments (global, in-register hi/lo split) ----
        const int ks = k0 + lg * 8;
        float xv[8];
        if (ks < K) {
            const float* xp = X + (size_t)arow * K + ks;
            float4 t0 = *(const float4*)(xp);
            float4 t1 = *(const float4*)(xp + 4);
            xv[0] = t0.x; xv[1] = t0.y; xv[2] = t0.z; xv[3] = t0.w;
            xv[4] = t1.x; xv[5] = t1.y; xv[6] = t1.z; xv[7] = t1.w;
        } else {
            #pragma unroll
            for (int j = 0; j < 8; ++j) xv[j] = 0.f;
        }
        bf16x8 ah, al;
        #pragma unroll
        for (int j = 0; j < 8; ++j) {
            unsigned short h = f2bf(xv[j]);
            ah[j] = (short)h;
            al[j] = (short)f2bf(xv[j] - __uint_as_float((unsigned)h << 16));
        }

        // ---- 10 col-tiles x 3 split MFMAs ----
        #pragma unroll
        for (int ct = 0; ct < 10; ++ct) {
            const int c = ct * 16 + lr;
            bf16x8 bh = *(const bf16x8*)&wsb[0][c][lg * 8];
            bf16x8 bl = *(const bf16x8*)&wsb[1][c][lg * 8];
            acc[ct] = __builtin_amdgcn_mfma_f32_16x16x32_bf16(ah, bh, acc[ct], 0, 0, 0);
            acc[ct] = __builtin_amdgcn_mfma_f32_16x16x32_bf16(al, bh, acc[ct], 0, 0, 0);
            acc[ct] = __builtin_amdgcn_mfma_f32_16x16x32_bf16(ah, bl, acc[ct], 0, 0, 0);
        }
    }

    // ---- epilogue: C row = (lane>>4)*4 + reg, col = lane&15 ----
    #pragma unroll
    for (int ct = 0; ct < 10; ++ct) {
        const int c = ct * 16 + lr;
        float* Yb = (c < 80) ? (Yl + c) : (Yr + (c - 80));
        #pragma unroll
        for (int j = 0; j < 4; ++j) {
            int r = base + w * 16 + lg * 4 + j;
            if (r < N) Yb[(size_t)r * HC] = acc[ct][j];
        }
    }
}

// ---------------- fused per-node attention + softmax + aggregate + elu ----------------
// Lane = head: 8-lane group per node, lane h holds head h's 10 channels in registers.
// Online softmax lane-local; defer-max THR=8 (exp2 domain): rescale branch ~never taken.

__global__ __launch_bounds__(256) void aggregate_kernel(
    const float* __restrict__ xl, const float* __restrict__ xr,
    const int* __restrict__ csr, const int* __restrict__ offsets,
    const float* __restrict__ att, const float* __restrict__ bias,
    float* __restrict__ xout, int N) {
    const int tid = threadIdx.x;
    const int n = blockIdx.x * 32 + (tid >> 3);
    const int h = tid & 7;
    if (n >= N) return;
    const float L2E = 1.4426950408889634f;

    float attv[10], xrv[10];
    #pragma unroll
    for (int j = 0; j < 5; ++j) {
        float2 a = *(const float2*)(att + h * CC + 2 * j);
        attv[2 * j] = a.x * L2E; attv[2 * j + 1] = a.y * L2E;
        float2 r = *(const float2*)(xr + (size_t)n * HC + h * CC + 2 * j);
        xrv[2 * j] = r.x; xrv[2 * j + 1] = r.y;
    }

    const int beg = offsets[n], end = offsets[n + 1];
    float m = -1e30f, s = 0.f;
    float acc[10];
    #pragma unroll
    for (int j = 0; j < 10; ++j) acc[j] = 0.f;

    int i = beg - 1;                   // iteration -1 = self loop
    while (__any(i < end)) {
        if (i < end) {
            int src = (i < beg) ? n : csr[i];
            const float* xp = xl + (size_t)src * HC + h * CC;
            float xv[10];
            #pragma unroll
            for (int j = 0; j < 5; ++j) {
                float2 v = *(const float2*)(xp + 2 * j);
                xv[2 * j] = v.x; xv[2 * j + 1] = v.y;
            }
            float e = 0.f;
            #pragma unroll
            for (int j = 0; j < 10; ++j) {
                float t = xv[j] + xrv[j];
                float lk = 0.6f * t + 0.4f * fabsf(t);  // leaky_relu(t, 0.2)
                e += lk * attv[j];
            }
            float diff = e - m;
            if (__builtin_expect(diff > 8.0f, 0)) {     // rare after iter 0
                float sc = exp2f(-diff);
                s = s * sc + 1.f;
                #pragma unroll
                for (int j = 0; j < 10; ++j) acc[j] = acc[j] * sc + xv[j];
                m = e;
            } else {
                float p = exp2f(diff);
                s += p;
                #pragma unroll
                for (int j = 0; j < 10; ++j) acc[j] += p * xv[j];
            }
        }
        ++i;
    }

    float inv = 1.f / s;
    float* op = xout + (size_t)n * HC + h * CC;
    #pragma unroll
    for (int j = 0; j < 5; ++j) {
        float2 b = *(const float2*)(bias + h * CC + 2 * j);
        float o0 = acc[2 * j] * inv + b.x;
        float o1 = acc[2 * j + 1] * inv + b.y;
        o0 = (o0 > 0.f) ? o0 : (__expf(o0) - 1.f);      // elu
        o1 = (o1 > 0.f) ? o1 : (__expf(o1) - 1.f);
        *(float2*)(op + 2 * j) = make_float2(o0, o1);
    }
}

extern "C" void kernel_launch(void* const* d_in, const int* in_sizes, int n_in,
                              void* d_out, int out_size, void* d_ws, size_t ws_size,
                              hipStream_t stream) {
    int N = out_size / HC;       // 100000
    int E = in_sizes[1] / 2;     // 1000000
    int F = in_sizes[0] / N;     // 128

    const float* x   = (const float*)d_in[0];
    const int*   ei  = (const int*)d_in[1];
    const float* Wl[3]  = {(const float*)d_in[2], (const float*)d_in[6],  (const float*)d_in[10]};
    const float* Wr[3]  = {(const float*)d_in[3], (const float*)d_in[7],  (const float*)d_in[11]};
    const float* att[3] = {(const float*)d_in[4], (const float*)d_in[8],  (const float*)d_in[12]};
    const float* bb[3]  = {(const float*)d_in[5], (const float*)d_in[9],  (const float*)d_in[13]};

    size_t NF = (size_t)N * HC;
    float* xl = (float*)d_ws;
    float* xr = xl + NF;
    float* xb = xr + NF;
    int* counts  = (int*)(xb + NF);
    int* offsets = counts + (N + 1);
    int* cursor  = offsets + (N + 1);
    int* csr     = cursor + N;

    const int* srcv = ei;
    const int* dstv = ei + E;

    hipMemsetAsync(counts, 0, (size_t)(N + 1) * sizeof(int), stream);
    hist_kernel<<<1024, 256, 0, stream>>>(dstv, counts, E);
    scan_kernel<<<1, 1024, 0, stream>>>(counts, offsets, N);
    hipMemcpyAsync(cursor, offsets, (size_t)N * sizeof(int), hipMemcpyDeviceToDevice, stream);
    scatter_kernel<<<1024, 256, 0, stream>>>(srcv, dstv, cursor, csr, E);

    for (int l = 0; l < 3; ++l) {
        const float* xin = (l == 0) ? x : xb;
        int K = (l == 0) ? F : HC;
        gemm_mfma<<<(N + 63) / 64, 256, 0, stream>>>(xin, Wl[l], Wr[l], xl, xr, N, K);
        float* xout = (l == 2) ? (float*)d_out : xb;
        aggregate_kernel<<<(N + 31) / 32, 256, 0, stream>>>(xl, xr, csr, offsets,
                                                            att[l], bb[l], xout, N);
    }
}